// Round 1
// baseline (251.557 us; speedup 1.0000x reference)
//
#include <hip/hip_runtime.h>

// Problem constants: B=16, Q=64, K=1024, H=256, Dv=256
#define LOG2E 1.4426950408889634f
#define TANH_SCALE 2.8853900817779268f   // 2*log2(e), folded into projections
#define NEG_BIG -1e30f

// ---------------------------------------------------------------------------
// Projection: out[m][n] = TANH_SCALE * sum_d A[m][d] * W[n][d]   (K=N=256)
// 64x64 tile per block, 256 threads, 4x4 microtile, K-major LDS tiles.
// ---------------------------------------------------------------------------
__global__ __launch_bounds__(256) void proj_kernel(const float* __restrict__ A,
                                                   const float* __restrict__ W,
                                                   float* __restrict__ out) {
    __shared__ float As[64][68];   // [k][m], pad->16B aligned rows
    __shared__ float Ws[64][68];   // [k][n]
    const int tid = threadIdx.x;
    const int m0 = blockIdx.x * 64;
    const int n0 = blockIdx.y * 64;
    const int tm = tid >> 4;    // 0..15
    const int tn = tid & 15;    // 0..15
    float acc[4][4] = {};

    for (int kt = 0; kt < 256; kt += 64) {
        __syncthreads();
        #pragma unroll
        for (int i = 0; i < 4; ++i) {
            int f   = tid + 256 * i;        // 0..1023
            int row = f >> 4;               // 0..63
            int c4  = (f & 15) << 2;        // 0..60
            float4 av = *reinterpret_cast<const float4*>(&A[(m0 + row) * 256 + kt + c4]);
            As[c4 + 0][row] = av.x;
            As[c4 + 1][row] = av.y;
            As[c4 + 2][row] = av.z;
            As[c4 + 3][row] = av.w;
            float4 wv4 = *reinterpret_cast<const float4*>(&W[(n0 + row) * 256 + kt + c4]);
            Ws[c4 + 0][row] = wv4.x;
            Ws[c4 + 1][row] = wv4.y;
            Ws[c4 + 2][row] = wv4.z;
            Ws[c4 + 3][row] = wv4.w;
        }
        __syncthreads();
        #pragma unroll 8
        for (int kk = 0; kk < 64; ++kk) {
            float4 af = *reinterpret_cast<const float4*>(&As[kk][tm << 2]);
            float4 wf = *reinterpret_cast<const float4*>(&Ws[kk][tn << 2]);
            float a_[4] = {af.x, af.y, af.z, af.w};
            float w_[4] = {wf.x, wf.y, wf.z, wf.w};
            #pragma unroll
            for (int i = 0; i < 4; ++i)
                #pragma unroll
                for (int j = 0; j < 4; ++j)
                    acc[i][j] += a_[i] * w_[j];
        }
    }
    #pragma unroll
    for (int i = 0; i < 4; ++i) {
        float4 o;
        o.x = acc[i][0] * TANH_SCALE;
        o.y = acc[i][1] * TANH_SCALE;
        o.z = acc[i][2] * TANH_SCALE;
        o.w = acc[i][3] * TANH_SCALE;
        *reinterpret_cast<float4*>(&out[(m0 + (tm << 2) + i) * 256 + n0 + (tn << 2)]) = o;
    }
}

// ---------------------------------------------------------------------------
// Fused additive attention:
//   s[b,q,k] = sum_h (-2*wv[h]) * rcp(exp2(qp'[h]+kp'[k,h]) + 1)   (+const, cancels)
//   online masked softmax over k, out = attn @ values
// Grid: 256 blocks = (b:16) x (qtile:16); 256 threads = 4 waves, 1 q per wave.
// 64-key chunks; kp chunk staged in XOR-swizzled LDS (bank-conflict-free).
// ---------------------------------------------------------------------------
__global__ __launch_bounds__(256) void attn_kernel(const float* __restrict__ qp,
                                                   const float* __restrict__ kp,
                                                   const float* __restrict__ values,
                                                   const int* __restrict__ valid_lens,
                                                   const float* __restrict__ wv,
                                                   float* __restrict__ out) {
    __shared__ float4 kp_t[64 * 64];     // 64 keys x 256 h, f4-swizzled: 64 KiB
    __shared__ float4 qp_f4[4 * 64];     // 4 q rows
    __shared__ float4 wv2_f4[64];        // -2*wv
    __shared__ float  p_lds[4][64];

    const int tid  = threadIdx.x;
    const int w    = tid >> 6;           // wave id 0..3
    const int lane = tid & 63;
    const int b    = blockIdx.x >> 4;
    const int q0   = (blockIdx.x & 15) << 2;

    if (tid < 64) {
        float4 t = *reinterpret_cast<const float4*>(&wv[tid << 2]);
        float4 s;
        s.x = -2.0f * t.x; s.y = -2.0f * t.y; s.z = -2.0f * t.z; s.w = -2.0f * t.w;
        wv2_f4[tid] = s;
    }
    // each wave stages its own q row (row w): no cross-wave dependency
    qp_f4[(w << 6) + lane] =
        *reinterpret_cast<const float4*>(&qp[((b << 6) + q0 + w) * 256 + (lane << 2)]);

    const int vl = valid_lens[b];
    const int nchunks = (vl + 63) >> 6;

    float m = -INFINITY, l = 0.0f;
    float acc0 = 0.f, acc1 = 0.f, acc2 = 0.f, acc3 = 0.f;

    for (int c = 0; c < nchunks; ++c) {
        __syncthreads();   // all waves done with previous kp chunk (also covers wv2/qp)
        {   // cooperative load: kp rows c*64..c*64+63 (always in-bounds, K=1024)
            const float4* src = reinterpret_cast<const float4*>(&kp[(b * 1024 + (c << 6)) * 256]);
            #pragma unroll
            for (int i = 0; i < 16; ++i) {
                int f   = tid + 256 * i;     // f4 index 0..4095
                int row = f >> 6;
                int col = f & 63;
                kp_t[(row << 6) + (col ^ (row & 7))] = src[f];
            }
        }
        __syncthreads();

        // ---- score for key k = c*64 + lane ----
        float s0 = 0.f, s1 = 0.f, s2 = 0.f, s3 = 0.f;
        const int krow = lane << 6;
        const int ksw  = lane & 7;
        const int qrow = w << 6;
        #pragma unroll 8
        for (int jh = 0; jh < 64; ++jh) {
            float4 kv = kp_t[krow + (jh ^ ksw)];
            float4 qv = qp_f4[qrow + jh];
            float4 wvv = wv2_f4[jh];
            s0 += wvv.x * __builtin_amdgcn_rcpf(__builtin_amdgcn_exp2f(kv.x + qv.x) + 1.0f);
            s1 += wvv.y * __builtin_amdgcn_rcpf(__builtin_amdgcn_exp2f(kv.y + qv.y) + 1.0f);
            s2 += wvv.z * __builtin_amdgcn_rcpf(__builtin_amdgcn_exp2f(kv.z + qv.z) + 1.0f);
            s3 += wvv.w * __builtin_amdgcn_rcpf(__builtin_amdgcn_exp2f(kv.w + qv.w) + 1.0f);
        }
        float s = (s0 + s1) + (s2 + s3);
        if ((c << 6) + lane >= vl) s = NEG_BIG;

        // ---- online softmax (per-wave) ----
        float mc = s;
        #pragma unroll
        for (int o = 32; o > 0; o >>= 1) mc = fmaxf(mc, __shfl_xor(mc, o));
        float m_new = fmaxf(m, mc);
        float r = __builtin_amdgcn_exp2f((m - m_new) * LOG2E);
        float p = __builtin_amdgcn_exp2f((s - m_new) * LOG2E);
        float lc = p;
        #pragma unroll
        for (int o = 32; o > 0; o >>= 1) lc += __shfl_xor(lc, o);
        l = l * r + lc;
        m = m_new;
        acc0 *= r; acc1 *= r; acc2 *= r; acc3 *= r;
        p_lds[w][lane] = p;   // same-wave produce/consume: no barrier needed

        // ---- PV: out[d] += p[j] * values[k=c*64+j][d], d = lane*4..lane*4+3 ----
        const int nv = min(64, vl - (c << 6));
        const float* vsrc = &values[(b * 1024 + (c << 6)) * 256 + (lane << 2)];
        if (nv == 64) {
            #pragma unroll 8
            for (int j = 0; j < 64; ++j) {
                float pj = p_lds[w][j];
                float4 v = *reinterpret_cast<const float4*>(&vsrc[j * 256]);
                acc0 += pj * v.x; acc1 += pj * v.y; acc2 += pj * v.z; acc3 += pj * v.w;
            }
        } else {
            for (int j = 0; j < nv; ++j) {
                float pj = p_lds[w][j];
                float4 v = *reinterpret_cast<const float4*>(&vsrc[j * 256]);
                acc0 += pj * v.x; acc1 += pj * v.y; acc2 += pj * v.z; acc3 += pj * v.w;
            }
        }
    }

    const float inv_l = 1.0f / l;
    float4 o;
    o.x = acc0 * inv_l; o.y = acc1 * inv_l; o.z = acc2 * inv_l; o.w = acc3 * inv_l;
    *reinterpret_cast<float4*>(&out[(((b << 6) + q0 + w) * 256) + (lane << 2)]) = o;
}

extern "C" void kernel_launch(void* const* d_in, const int* in_sizes, int n_in,
                              void* d_out, int out_size, void* d_ws, size_t ws_size,
                              hipStream_t stream) {
    const float* queries    = (const float*)d_in[0];  // [16,64,256]
    const float* keys       = (const float*)d_in[1];  // [16,1024,256]
    const float* values     = (const float*)d_in[2];  // [16,1024,256]
    const int*   valid_lens = (const int*)d_in[3];    // [16]
    const float* Wq         = (const float*)d_in[4];  // [256,256]
    const float* Wk         = (const float*)d_in[5];  // [256,256]
    const float* wv         = (const float*)d_in[6];  // [256]
    float* out = (float*)d_out;                       // [16,64,256]

    float* qp = (float*)d_ws;                 // 1024*256 floats  (1 MiB)
    float* kp = qp + 1024 * 256;              // 16384*256 floats (16 MiB)

    // qp' = TANH_SCALE * queries @ Wq^T : M=1024
    proj_kernel<<<dim3(16, 4), 256, 0, stream>>>(queries, Wq, qp);
    // kp' = TANH_SCALE * keys @ Wk^T : M=16384
    proj_kernel<<<dim3(256, 4), 256, 0, stream>>>(keys, Wk, kp);
    // fused scores + masked softmax + PV
    attn_kernel<<<dim3(256), 256, 0, stream>>>(qp, kp, values, valid_lens, wv, out);
}

// Round 2
// 181.781 us; speedup vs baseline: 1.3838x; 1.3838x over previous
//
#include <hip/hip_runtime.h>

// B=16, Q=64, K=1024, H=256, Dv=256
#define LOG2E 1.4426950408889634f
#define TANH_SCALE 2.8853900817779268f   // 2*log2(e), folded into projections
#define NEG_BIG -1e30f

typedef __attribute__((ext_vector_type(8))) short bf16x8;
typedef __attribute__((ext_vector_type(4))) float f32x4;

static __device__ __forceinline__ short f2bf(float f) {
    unsigned u = __builtin_bit_cast(unsigned, f);
    u += 0x7fffu + ((u >> 16) & 1u);     // round-to-nearest-even
    return (short)(u >> 16);
}

// ---------------------------------------------------------------------------
// Fused projections via bf16 MFMA: dst[m][n] = TANH_SCALE * sum_d A[m][d]*W[n][d]
// mtile<16 -> queries@Wq^T (M=1024), else keys@Wk^T (M=16384). N=K=256.
// Block: 4 waves (2x2), wave = 32m x 64n (2 m-frags x 4 n-frags), K-loop of 8.
// Fragments loaded directly from global (W is L1/L2 resident), fp32->bf16 inline.
// ---------------------------------------------------------------------------
__global__ __launch_bounds__(256) void proj_mfma(const float* __restrict__ queries,
                                                 const float* __restrict__ keys,
                                                 const float* __restrict__ Wq,
                                                 const float* __restrict__ Wk,
                                                 float* __restrict__ qp,
                                                 float* __restrict__ kp) {
    const int mtile = blockIdx.x;
    const float* A; const float* W; float* dst; int m0;
    if (mtile < 16) { A = queries; W = Wq; dst = qp; m0 = mtile * 64; }
    else            { A = keys;    W = Wk; dst = kp; m0 = (mtile - 16) * 64; }

    const int tid  = threadIdx.x;
    const int w    = tid >> 6;
    const int lane = tid & 63;
    const int wm   = w >> 1, wn = w & 1;
    const int row_base = m0 + wm * 32;
    const int col_base = blockIdx.y * 128 + wn * 64;
    const int r  = lane & 15;
    const int kq = lane >> 4;            // 0..3

    f32x4 acc[2][4] = {};

    #pragma unroll
    for (int ks = 0; ks < 8; ++ks) {
        const int k0 = ks * 32 + kq * 8;   // 8 contiguous k per lane
        bf16x8 a[2], bb[4];
        #pragma unroll
        for (int mi = 0; mi < 2; ++mi) {
            const float* p = &A[(row_base + mi * 16 + r) * 256 + k0];
            float4 f0 = *reinterpret_cast<const float4*>(p);
            float4 f1 = *reinterpret_cast<const float4*>(p + 4);
            a[mi] = (bf16x8){f2bf(f0.x), f2bf(f0.y), f2bf(f0.z), f2bf(f0.w),
                             f2bf(f1.x), f2bf(f1.y), f2bf(f1.z), f2bf(f1.w)};
        }
        #pragma unroll
        for (int nj = 0; nj < 4; ++nj) {
            const float* p = &W[(col_base + nj * 16 + r) * 256 + k0];
            float4 f0 = *reinterpret_cast<const float4*>(p);
            float4 f1 = *reinterpret_cast<const float4*>(p + 4);
            bb[nj] = (bf16x8){f2bf(f0.x), f2bf(f0.y), f2bf(f0.z), f2bf(f0.w),
                              f2bf(f1.x), f2bf(f1.y), f2bf(f1.z), f2bf(f1.w)};
        }
        #pragma unroll
        for (int mi = 0; mi < 2; ++mi)
            #pragma unroll
            for (int nj = 0; nj < 4; ++nj)
                acc[mi][nj] = __builtin_amdgcn_mfma_f32_16x16x32_bf16(a[mi], bb[nj], acc[mi][nj], 0, 0, 0);
    }

    // C/D layout: col = lane&15, row = (lane>>4)*4 + reg   [verified mapping]
    #pragma unroll
    for (int mi = 0; mi < 2; ++mi)
        #pragma unroll
        for (int nj = 0; nj < 4; ++nj)
            #pragma unroll
            for (int t = 0; t < 4; ++t)
                dst[(row_base + mi * 16 + kq * 4 + t) * 256 + col_base + nj * 16 + r] =
                    acc[mi][nj][t] * TANH_SCALE;
}

// ---------------------------------------------------------------------------
// Split-K fused attention. Grid (qt:16, b:16, seg:4); 4 waves, 1 q per wave.
// Segment = 256 keys, processed as 64-key chunks staged in LDS in two h-halves
// (32KB) -> 4 blocks/CU. Writes unnormalized partials (m, l, acc[256]) to ws.
// ---------------------------------------------------------------------------
__global__ __launch_bounds__(256) void attn_kernel(const float* __restrict__ qp,
                                                   const float* __restrict__ kp,
                                                   const float* __restrict__ values,
                                                   const int* __restrict__ valid_lens,
                                                   const float* __restrict__ wv,
                                                   float* __restrict__ part_acc,
                                                   float* __restrict__ part_m,
                                                   float* __restrict__ part_l) {
    __shared__ float4 kp_t[64 * 32];     // 64 keys x 128 h (one half), swizzled: 32 KiB
    __shared__ float4 qp_f4[4 * 64];     // 4 q rows x 256 h
    __shared__ float4 wv2_f4[64];        // -2*wv
    __shared__ float  p_lds[4][64];

    const int tid  = threadIdx.x;
    const int w    = tid >> 6;
    const int lane = tid & 63;
    const int qt = blockIdx.x, b = blockIdx.y, seg = blockIdx.z;
    const int q0 = qt << 2;
    const int q  = q0 + w;
    const int vl = valid_lens[b];
    const int kstart = seg << 8;
    const int pidx = (b * 64 + q) * 4 + seg;

    if (kstart >= vl) {                  // inactive segment: neutral partials
        f32x4 z = {0.f, 0.f, 0.f, 0.f};
        *reinterpret_cast<f32x4*>(&part_acc[pidx * 256 + lane * 4]) = z;
        if (lane == 0) { part_m[pidx] = NEG_BIG; part_l[pidx] = 0.0f; }
        return;
    }

    if (tid < 64) {
        float4 t = *reinterpret_cast<const float4*>(&wv[tid << 2]);
        float4 s2;
        s2.x = -2.0f * t.x; s2.y = -2.0f * t.y; s2.z = -2.0f * t.z; s2.w = -2.0f * t.w;
        wv2_f4[tid] = s2;
    }
    qp_f4[(w << 6) + lane] =
        *reinterpret_cast<const float4*>(&qp[(b * 64 + q) * 256 + (lane << 2)]);

    const int kend = min(kstart + 256, vl);
    const int nchunks = (kend - kstart + 63) >> 6;

    float m = -INFINITY, l = 0.0f;
    float acc0 = 0.f, acc1 = 0.f, acc2 = 0.f, acc3 = 0.f;

    for (int c = 0; c < nchunks; ++c) {
        const int ck = kstart + (c << 6);
        float s0 = 0.f, s1 = 0.f, s2 = 0.f, s3 = 0.f;

        #pragma unroll
        for (int half = 0; half < 2; ++half) {
            __syncthreads();             // previous consumers done (also covers wv2/qp first time)
            {   // stage 64 keys x 128 h (rows always in-bounds: kstart+256 <= 1024)
                const float4* src = reinterpret_cast<const float4*>(&kp[(b * 1024 + ck) * 256]) + half * 32;
                #pragma unroll
                for (int i = 0; i < 8; ++i) {
                    int f   = tid + 256 * i;   // 0..2047
                    int row = f >> 5;          // 0..63
                    int col = f & 31;          // f4 col within half
                    kp_t[(row << 5) + (col ^ (row & 7))] = src[row * 64 + col];
                }
            }
            __syncthreads();

            const int krow = lane << 5;
            const int ksw  = lane & 7;
            const int hq   = half << 5;
            #pragma unroll 8
            for (int jh = 0; jh < 32; ++jh) {
                float4 kv  = kp_t[krow + (jh ^ ksw)];
                float4 qv  = qp_f4[(w << 6) + hq + jh];
                float4 wvv = wv2_f4[hq + jh];
                s0 += wvv.x * __builtin_amdgcn_rcpf(__builtin_amdgcn_exp2f(kv.x + qv.x) + 1.0f);
                s1 += wvv.y * __builtin_amdgcn_rcpf(__builtin_amdgcn_exp2f(kv.y + qv.y) + 1.0f);
                s2 += wvv.z * __builtin_amdgcn_rcpf(__builtin_amdgcn_exp2f(kv.z + qv.z) + 1.0f);
                s3 += wvv.w * __builtin_amdgcn_rcpf(__builtin_amdgcn_exp2f(kv.w + qv.w) + 1.0f);
            }
        }
        float s = (s0 + s1) + (s2 + s3);
        if (ck + lane >= vl) s = NEG_BIG;

        // online softmax (per-wave)
        float mc = s;
        #pragma unroll
        for (int o = 32; o > 0; o >>= 1) mc = fmaxf(mc, __shfl_xor(mc, o));
        float m_new = fmaxf(m, mc);
        float rr = __builtin_amdgcn_exp2f((m - m_new) * LOG2E);
        float p  = __builtin_amdgcn_exp2f((s - m_new) * LOG2E);
        float lc = p;
        #pragma unroll
        for (int o = 32; o > 0; o >>= 1) lc += __shfl_xor(lc, o);
        l = l * rr + lc;
        m = m_new;
        acc0 *= rr; acc1 *= rr; acc2 *= rr; acc3 *= rr;
        p_lds[w][lane] = p;              // same-wave produce/consume

        const int nv = min(64, kend - ck);
        const float* vsrc = &values[(b * 1024 + ck) * 256 + (lane << 2)];
        if (nv == 64) {
            #pragma unroll 8
            for (int j = 0; j < 64; ++j) {
                float pj = p_lds[w][j];
                float4 v = *reinterpret_cast<const float4*>(&vsrc[j * 256]);
                acc0 += pj * v.x; acc1 += pj * v.y; acc2 += pj * v.z; acc3 += pj * v.w;
            }
        } else {
            for (int j = 0; j < nv; ++j) {
                float pj = p_lds[w][j];
                float4 v = *reinterpret_cast<const float4*>(&vsrc[j * 256]);
                acc0 += pj * v.x; acc1 += pj * v.y; acc2 += pj * v.z; acc3 += pj * v.w;
            }
        }
    }

    if (lane == 0) { part_m[pidx] = m; part_l[pidx] = l; }
    f32x4 av = {acc0, acc1, acc2, acc3};
    *reinterpret_cast<f32x4*>(&part_acc[pidx * 256 + lane * 4]) = av;
}

// ---------------------------------------------------------------------------
// Combine 4 split-K partials per (b,q). Grid 256 blocks; wave w -> q0+w,
// lane -> 4 dims.
// ---------------------------------------------------------------------------
__global__ __launch_bounds__(256) void combine_kernel(const float* __restrict__ part_acc,
                                                      const float* __restrict__ part_m,
                                                      const float* __restrict__ part_l,
                                                      float* __restrict__ out) {
    const int tid  = threadIdx.x;
    const int w    = tid >> 6;
    const int lane = tid & 63;
    const int b  = blockIdx.x >> 4;
    const int qt = blockIdx.x & 15;
    const int q  = (qt << 2) + w;
    const int base = (b * 64 + q) * 4;

    float m0 = part_m[base + 0], m1 = part_m[base + 1];
    float m2 = part_m[base + 2], m3 = part_m[base + 3];
    float M = fmaxf(fmaxf(m0, m1), fmaxf(m2, m3));
    float w0 = __builtin_amdgcn_exp2f((m0 - M) * LOG2E);
    float w1 = __builtin_amdgcn_exp2f((m1 - M) * LOG2E);
    float w2 = __builtin_amdgcn_exp2f((m2 - M) * LOG2E);
    float w3 = __builtin_amdgcn_exp2f((m3 - M) * LOG2E);
    float L = w0 * part_l[base + 0] + w1 * part_l[base + 1]
            + w2 * part_l[base + 2] + w3 * part_l[base + 3];

    const float* a0 = &part_acc[(base + 0) * 256 + (lane << 2)];
    float4 v0 = *reinterpret_cast<const float4*>(a0);
    float4 v1 = *reinterpret_cast<const float4*>(a0 + 256);
    float4 v2 = *reinterpret_cast<const float4*>(a0 + 512);
    float4 v3 = *reinterpret_cast<const float4*>(a0 + 768);
    float invL = 1.0f / L;
    float4 o;
    o.x = (w0 * v0.x + w1 * v1.x + w2 * v2.x + w3 * v3.x) * invL;
    o.y = (w0 * v0.y + w1 * v1.y + w2 * v2.y + w3 * v3.y) * invL;
    o.z = (w0 * v0.z + w1 * v1.z + w2 * v2.z + w3 * v3.z) * invL;
    o.w = (w0 * v0.w + w1 * v1.w + w2 * v2.w + w3 * v3.w) * invL;
    *reinterpret_cast<float4*>(&out[(b * 64 + q) * 256 + (lane << 2)]) = o;
}

extern "C" void kernel_launch(void* const* d_in, const int* in_sizes, int n_in,
                              void* d_out, int out_size, void* d_ws, size_t ws_size,
                              hipStream_t stream) {
    const float* queries    = (const float*)d_in[0];  // [16,64,256]
    const float* keys       = (const float*)d_in[1];  // [16,1024,256]
    const float* values     = (const float*)d_in[2];  // [16,1024,256]
    const int*   valid_lens = (const int*)d_in[3];    // [16]
    const float* Wq         = (const float*)d_in[4];  // [256,256]
    const float* Wk         = (const float*)d_in[5];  // [256,256]
    const float* wv         = (const float*)d_in[6];  // [256]
    float* out = (float*)d_out;                       // [16,64,256]

    float* qp       = (float*)d_ws;          // 1024*256
    float* kp       = qp + 262144;           // 16384*256
    float* part_acc = kp + 4194304;          // 16*64*4*256
    float* part_m   = part_acc + 1048576;    // 4096
    float* part_l   = part_m + 4096;         // 4096

    // both projections in one launch: mtile 0..15 -> qp, 16..271 -> kp
    proj_mfma<<<dim3(272, 2), 256, 0, stream>>>(queries, keys, Wq, Wk, qp, kp);
    // split-K fused scores + masked online softmax + PV partials
    attn_kernel<<<dim3(16, 16, 4), 256, 0, stream>>>(qp, kp, values, valid_lens, wv,
                                                     part_acc, part_m, part_l);
    // merge partials
    combine_kernel<<<dim3(256), 256, 0, stream>>>(part_acc, part_m, part_l, out);
}

// Round 3
// 162.851 us; speedup vs baseline: 1.5447x; 1.1162x over previous
//
#include <hip/hip_runtime.h>

// B=16, Q=64, K=1024, H=256, Dv=256
#define LOG2E 1.4426950408889634f
#define TANH_SCALE 2.8853900817779268f   // 2*log2(e)
#define NEG_BIG -1e30f

typedef __attribute__((ext_vector_type(8))) short bf16x8;
typedef __attribute__((ext_vector_type(4))) float f32x4;

static __device__ __forceinline__ short f2bf(float f) {
    unsigned u = __builtin_bit_cast(unsigned, f);
    u += 0x7fffu + ((u >> 16) & 1u);     // round-to-nearest-even
    return (short)(u >> 16);
}

// ---------------------------------------------------------------------------
// Projection via bf16 MFMA, epilogue outputs E = exp2(TANH_SCALE * (A@W^T)).
// mtile<16 -> queries (eq), else keys (ek). Block: 64M x 128N tile, 4 waves
// (2m x 2n), K-steps of 64 staged in LDS as bf16 with 16B-granule XOR swizzle.
// ---------------------------------------------------------------------------
__global__ __launch_bounds__(256) void proj_mfma(const float* __restrict__ queries,
                                                 const float* __restrict__ keys,
                                                 const float* __restrict__ Wq,
                                                 const float* __restrict__ Wk,
                                                 float* __restrict__ eq,
                                                 float* __restrict__ ek) {
    __shared__ char As[64 * 128];    // [64 m][64 k] bf16, swizzled granules (8 KB)
    __shared__ char Bs[128 * 128];   // [128 n][64 k] bf16, swizzled (16 KB)

    const int mtile = blockIdx.x;
    const float* A; const float* W; float* dst; int m0;
    if (mtile < 16) { A = queries; W = Wq; dst = eq; m0 = mtile << 6; }
    else            { A = keys;    W = Wk; dst = ek; m0 = (mtile - 16) << 6; }

    const int tid = threadIdx.x;
    const int w = tid >> 6, lane = tid & 63;
    const int wm = w >> 1, wn = w & 1;
    const int n0 = blockIdx.y << 7;
    const int r = lane & 15, kq = lane >> 4;

    f32x4 acc[2][4] = {};

    const int ra = tid >> 2, sa = tid & 3;   // A staging: row, 16-k segment
    const int rb = tid >> 1, hb = tid & 1;   // B staging: row, 32-k half

    for (int ks = 0; ks < 4; ++ks) {
        const int k0 = ks << 6;
        __syncthreads();
        {
            const float* srcA = &A[(m0 + ra) * 256 + k0 + (sa << 4)];
            #pragma unroll
            for (int g = 0; g < 2; ++g) {
                float4 f0 = *reinterpret_cast<const float4*>(srcA + (g << 3));
                float4 f1 = *reinterpret_cast<const float4*>(srcA + (g << 3) + 4);
                bf16x8 pk = {f2bf(f0.x), f2bf(f0.y), f2bf(f0.z), f2bf(f0.w),
                             f2bf(f1.x), f2bf(f1.y), f2bf(f1.z), f2bf(f1.w)};
                int byt = (ra << 7) + (((sa << 5) + (g << 4)) ^ ((ra & 7) << 4));
                *reinterpret_cast<bf16x8*>(As + byt) = pk;
            }
            const float* srcB = &W[(n0 + rb) * 256 + k0 + (hb << 5)];
            #pragma unroll
            for (int g = 0; g < 4; ++g) {
                float4 f0 = *reinterpret_cast<const float4*>(srcB + (g << 3));
                float4 f1 = *reinterpret_cast<const float4*>(srcB + (g << 3) + 4);
                bf16x8 pk = {f2bf(f0.x), f2bf(f0.y), f2bf(f0.z), f2bf(f0.w),
                             f2bf(f1.x), f2bf(f1.y), f2bf(f1.z), f2bf(f1.w)};
                int byt = (rb << 7) + (((hb << 6) + (g << 4)) ^ ((rb & 7) << 4));
                *reinterpret_cast<bf16x8*>(Bs + byt) = pk;
            }
        }
        __syncthreads();

        bf16x8 af[2][2], bfr[4][2];
        #pragma unroll
        for (int kf = 0; kf < 2; ++kf) {
            #pragma unroll
            for (int mi = 0; mi < 2; ++mi) {
                int row = (wm << 5) + (mi << 4) + r;
                int byt = (row << 7) + (((kf << 6) + (kq << 4)) ^ ((row & 7) << 4));
                af[mi][kf] = *reinterpret_cast<const bf16x8*>(As + byt);
            }
            #pragma unroll
            for (int nj = 0; nj < 4; ++nj) {
                int row = (wn << 6) + (nj << 4) + r;
                int byt = (row << 7) + (((kf << 6) + (kq << 4)) ^ ((row & 7) << 4));
                bfr[nj][kf] = *reinterpret_cast<const bf16x8*>(Bs + byt);
            }
        }
        #pragma unroll
        for (int kf = 0; kf < 2; ++kf)
            #pragma unroll
            for (int mi = 0; mi < 2; ++mi)
                #pragma unroll
                for (int nj = 0; nj < 4; ++nj)
                    acc[mi][nj] = __builtin_amdgcn_mfma_f32_16x16x32_bf16(
                        af[mi][kf], bfr[nj][kf], acc[mi][nj], 0, 0, 0);
    }

    // C/D mapping: col = lane&15 (r), row = (lane>>4)*4 + t
    #pragma unroll
    for (int mi = 0; mi < 2; ++mi)
        #pragma unroll
        for (int nj = 0; nj < 4; ++nj)
            #pragma unroll
            for (int t = 0; t < 4; ++t) {
                int row = m0 + (wm << 5) + (mi << 4) + (kq << 2) + t;
                int col = n0 + (wn << 6) + (nj << 4) + r;
                dst[row * 256 + col] = __builtin_amdgcn_exp2f(TANH_SCALE * acc[mi][nj][t]);
            }
}

// ---------------------------------------------------------------------------
// Split-K fused attention. Grid (qt:8, b:16, seg:8); 4 waves, 2 q per wave.
// score = -2 * sum_h wv[h] * rcp(1 + Eq[h]*Ek[k,h])  (const term cancels in SM)
// 64-key chunks of Ek staged in LDS in two 128-h halves (32 KB, swizzled);
// Eq/wv read as wave-uniform broadcast loads (L1). Partials to ws.
// ---------------------------------------------------------------------------
__global__ __launch_bounds__(256) void attn_kernel(const float* __restrict__ eq,
                                                   const float* __restrict__ ek,
                                                   const float* __restrict__ values,
                                                   const int* __restrict__ valid_lens,
                                                   const float* __restrict__ wv,
                                                   float* __restrict__ part_acc,
                                                   float* __restrict__ part_m,
                                                   float* __restrict__ part_l) {
    __shared__ float4 ek_lds[64 * 32];   // [64 k][32 f4-h] swizzled, 32 KB
    __shared__ float p_lds[8][64];

    const int tid = threadIdx.x;
    const int w = tid >> 6, lane = tid & 63;
    const int qt = blockIdx.x, b = blockIdx.y, seg = blockIdx.z;
    const int q0 = (qt << 3) + (w << 1);
    const int vl = valid_lens[b];
    const int kstart = seg << 7;
    const int pidx0 = (((b << 6) + q0) << 3) + seg;

    if (kstart >= vl) {                  // inactive segment: neutral partials
        f32x4 z = {0.f, 0.f, 0.f, 0.f};
        *reinterpret_cast<f32x4*>(&part_acc[(size_t)pidx0 * 256 + (lane << 2)]) = z;
        *reinterpret_cast<f32x4*>(&part_acc[(size_t)(pidx0 + 8) * 256 + (lane << 2)]) = z;
        if (lane == 0) {
            part_m[pidx0] = NEG_BIG;     part_l[pidx0] = 0.f;
            part_m[pidx0 + 8] = NEG_BIG; part_l[pidx0 + 8] = 0.f;
        }
        return;
    }

    const float4* eq0 = reinterpret_cast<const float4*>(&eq[((b << 6) + q0) * 256]);
    const float4* eq1 = reinterpret_cast<const float4*>(&eq[((b << 6) + q0 + 1) * 256]);
    const float4* wv4 = reinterpret_cast<const float4*>(wv);

    const int kend = min(kstart + 128, vl);
    const int nchunks = (kend - kstart + 63) >> 6;

    float mA = -INFINITY, lA = 0.f, mB = -INFINITY, lB = 0.f;
    f32x4 accA = {0.f, 0.f, 0.f, 0.f}, accB = {0.f, 0.f, 0.f, 0.f};

    const int krow = lane << 5;
    const int ksw = lane & 7;

    for (int c = 0; c < nchunks; ++c) {
        const int ck = kstart + (c << 6);
        float s0 = 0.f, s1 = 0.f;

        #pragma unroll
        for (int half = 0; half < 2; ++half) {
            __syncthreads();             // previous consumers of ek_lds done
            {
                const float4* src =
                    reinterpret_cast<const float4*>(&ek[(size_t)(b * 1024 + ck) * 256]) + (half << 5);
                #pragma unroll
                for (int i = 0; i < 8; ++i) {
                    int d = (i << 8) + tid;
                    int row = d >> 5, col = d & 31;
                    ek_lds[(row << 5) + (col ^ (row & 7))] = src[row * 64 + col];
                }
            }
            __syncthreads();

            const int hoff = half << 5;
            #pragma unroll 8
            for (int jh = 0; jh < 32; ++jh) {
                float4 kv = ek_lds[krow + (jh ^ ksw)];
                float4 qa = eq0[hoff + jh];      // wave-uniform broadcast (L1)
                float4 qb = eq1[hoff + jh];
                float4 wc = wv4[hoff + jh];
                s0 += wc.x * __builtin_amdgcn_rcpf(fmaf(kv.x, qa.x, 1.0f));
                s0 += wc.y * __builtin_amdgcn_rcpf(fmaf(kv.y, qa.y, 1.0f));
                s0 += wc.z * __builtin_amdgcn_rcpf(fmaf(kv.z, qa.z, 1.0f));
                s0 += wc.w * __builtin_amdgcn_rcpf(fmaf(kv.w, qa.w, 1.0f));
                s1 += wc.x * __builtin_amdgcn_rcpf(fmaf(kv.x, qb.x, 1.0f));
                s1 += wc.y * __builtin_amdgcn_rcpf(fmaf(kv.y, qb.y, 1.0f));
                s1 += wc.z * __builtin_amdgcn_rcpf(fmaf(kv.z, qb.z, 1.0f));
                s1 += wc.w * __builtin_amdgcn_rcpf(fmaf(kv.w, qb.w, 1.0f));
            }
        }
        float sA = -2.0f * s0;
        float sB = -2.0f * s1;
        if (ck + lane >= vl) { sA = NEG_BIG; sB = NEG_BIG; }

        // online softmax (per wave, per q)
        float mcA = sA, mcB = sB;
        #pragma unroll
        for (int o = 32; o > 0; o >>= 1) {
            mcA = fmaxf(mcA, __shfl_xor(mcA, o));
            mcB = fmaxf(mcB, __shfl_xor(mcB, o));
        }
        float mnA = fmaxf(mA, mcA), mnB = fmaxf(mB, mcB);
        float rA = __builtin_amdgcn_exp2f((mA - mnA) * LOG2E);
        float rB = __builtin_amdgcn_exp2f((mB - mnB) * LOG2E);
        float pA = __builtin_amdgcn_exp2f((sA - mnA) * LOG2E);
        float pB = __builtin_amdgcn_exp2f((sB - mnB) * LOG2E);
        float lcA = pA, lcB = pB;
        #pragma unroll
        for (int o = 32; o > 0; o >>= 1) {
            lcA += __shfl_xor(lcA, o);
            lcB += __shfl_xor(lcB, o);
        }
        lA = lA * rA + lcA; mA = mnA;
        lB = lB * rB + lcB; mB = mnB;
        accA *= rA; accB *= rB;
        p_lds[(w << 1) + 0][lane] = pA;  // same-wave produce/consume
        p_lds[(w << 1) + 1][lane] = pB;

        const int nv = min(64, kend - ck);
        const float* vsrc = &values[(size_t)(b * 1024 + ck) * 256 + (lane << 2)];
        if (nv == 64) {
            #pragma unroll 8
            for (int j = 0; j < 64; ++j) {
                float pa = p_lds[(w << 1)][j], pb = p_lds[(w << 1) + 1][j];
                float4 v = *reinterpret_cast<const float4*>(vsrc + j * 256);
                accA.x += pa * v.x; accA.y += pa * v.y; accA.z += pa * v.z; accA.w += pa * v.w;
                accB.x += pb * v.x; accB.y += pb * v.y; accB.z += pb * v.z; accB.w += pb * v.w;
            }
        } else {
            for (int j = 0; j < nv; ++j) {
                float pa = p_lds[(w << 1)][j], pb = p_lds[(w << 1) + 1][j];
                float4 v = *reinterpret_cast<const float4*>(vsrc + j * 256);
                accA.x += pa * v.x; accA.y += pa * v.y; accA.z += pa * v.z; accA.w += pa * v.w;
                accB.x += pb * v.x; accB.y += pb * v.y; accB.z += pb * v.z; accB.w += pb * v.w;
            }
        }
    }

    if (lane == 0) {
        part_m[pidx0] = mA;     part_l[pidx0] = lA;
        part_m[pidx0 + 8] = mB; part_l[pidx0 + 8] = lB;
    }
    *reinterpret_cast<f32x4*>(&part_acc[(size_t)pidx0 * 256 + (lane << 2)]) = accA;
    *reinterpret_cast<f32x4*>(&part_acc[(size_t)(pidx0 + 8) * 256 + (lane << 2)]) = accB;
}

// ---------------------------------------------------------------------------
// Combine 8 split-K partials per (b,q).
// ---------------------------------------------------------------------------
__global__ __launch_bounds__(256) void combine_kernel(const float* __restrict__ part_acc,
                                                      const float* __restrict__ part_m,
                                                      const float* __restrict__ part_l,
                                                      float* __restrict__ out) {
    const int tid = threadIdx.x;
    const int w = tid >> 6, lane = tid & 63;
    const int b = blockIdx.x >> 4, qt = blockIdx.x & 15;
    const int q = (qt << 2) + w;
    const int base = (((b << 6) + q) << 3);

    float mm[8], ll[8];
    #pragma unroll
    for (int i = 0; i < 8; ++i) { mm[i] = part_m[base + i]; ll[i] = part_l[base + i]; }
    float M = mm[0];
    #pragma unroll
    for (int i = 1; i < 8; ++i) M = fmaxf(M, mm[i]);
    float wt[8];
    float L = 0.f;
    #pragma unroll
    for (int i = 0; i < 8; ++i) {
        wt[i] = __builtin_amdgcn_exp2f((mm[i] - M) * LOG2E);
        L += wt[i] * ll[i];
    }
    float invL = 1.0f / L;
    float4 o = {0.f, 0.f, 0.f, 0.f};
    #pragma unroll
    for (int i = 0; i < 8; ++i) {
        float4 v = *reinterpret_cast<const float4*>(&part_acc[(size_t)(base + i) * 256 + (lane << 2)]);
        o.x += wt[i] * v.x; o.y += wt[i] * v.y; o.z += wt[i] * v.z; o.w += wt[i] * v.w;
    }
    o.x *= invL; o.y *= invL; o.z *= invL; o.w *= invL;
    *reinterpret_cast<float4*>(&out[((b << 6) + q) * 256 + (lane << 2)]) = o;
}

extern "C" void kernel_launch(void* const* d_in, const int* in_sizes, int n_in,
                              void* d_out, int out_size, void* d_ws, size_t ws_size,
                              hipStream_t stream) {
    const float* queries    = (const float*)d_in[0];  // [16,64,256]
    const float* keys       = (const float*)d_in[1];  // [16,1024,256]
    const float* values     = (const float*)d_in[2];  // [16,1024,256]
    const int*   valid_lens = (const int*)d_in[3];    // [16]
    const float* Wq         = (const float*)d_in[4];  // [256,256]
    const float* Wk         = (const float*)d_in[5];  // [256,256]
    const float* wv         = (const float*)d_in[6];  // [256]
    float* out = (float*)d_out;                       // [16,64,256]

    float* eqw      = (float*)d_ws;          // 1024*256            (1 MiB)
    float* ekw      = eqw + 262144;          // 16384*256           (16 MiB)
    float* part_acc = ekw + 4194304;         // 16*64*8*256         (8 MiB)
    float* part_m   = part_acc + 2097152;    // 8192
    float* part_l   = part_m + 8192;         // 8192

    // E-projections: mtile 0..15 -> eq, 16..271 -> ek
    proj_mfma<<<dim3(272, 2), 256, 0, stream>>>(queries, keys, Wq, Wk, eqw, ekw);
    // split-K fused scores + masked online softmax + PV partials
    attn_kernel<<<dim3(8, 16, 8), 256, 0, stream>>>(eqw, ekw, values, valid_lens, wv,
                                                    part_acc, part_m, part_l);
    // merge partials
    combine_kernel<<<dim3(256), 256, 0, stream>>>(part_acc, part_m, part_l, out);
}